// Round 1
// baseline (23730.608 us; speedup 1.0000x reference)
//
#include <hip/hip_runtime.h>

// ---------------------------------------------------------------------------
// Persistent 2-layer GRU for MI355X (gfx950).
// B=128, T=1024, INPUT=HIDDEN=OUT=512.
// Grid: 256 wgs x 256 thr, 1 wg/CU (LDS-forced). wg = (layer, mt, nt):
//   layer = wg>>7 ; mt = m-tile of 32 batch rows ; nt = 16 hidden cols (48 gate rows)
// Waves k-split K=512 into 4x128, LDS reduce, wave0 does gates + h stores.
// Hidden state passed between intervals as MFMA-fragment-layout bf16 hi/lo
// buffers in d_ws (double buffered). One 2-level grid barrier per interval.
// ---------------------------------------------------------------------------

#define TS   1024
#define HID  512
#define NWG  256
#define WGT  256

typedef __attribute__((ext_vector_type(8))) short bf16x8;
typedef __attribute__((ext_vector_type(8))) unsigned short u16x8;
typedef __attribute__((ext_vector_type(4))) unsigned short u16x4;
typedef __attribute__((ext_vector_type(4))) float f32x4;

#define WS_MASTER   4096
#define WS_HBUF     8192
#define HBUF_ELEMS  65536                       // 128*512 bf16 per buffer
#define WS_H1F      (WS_HBUF + 8 * HBUF_ELEMS * 2)   // fp32 [128][512]
#define WS_ZERO     (WS_HBUF + 8 * HBUF_ELEMS * 2)   // barrier + h buffers

__device__ __forceinline__ unsigned short f2bf(float f) {
    unsigned u = __float_as_uint(f);
    u += 0x7FFFu + ((u >> 16) & 1u);            // round-to-nearest-even
    return (unsigned short)(u >> 16);
}
__device__ __forceinline__ float bf2f(unsigned short s) {
    return __uint_as_float(((unsigned)s) << 16);
}
__device__ __forceinline__ float sigm(float v) { return 1.0f / (1.0f + __expf(-v)); }
__device__ __forceinline__ float tanh_(float v) { return 1.0f - 2.0f / (1.0f + __expf(2.0f * v)); }

__global__ void __launch_bounds__(WGT, 1)
gru_persistent(const float* __restrict__ x,
               const float* __restrict__ wi0, const float* __restrict__ wh0,
               const float* __restrict__ bi0, const float* __restrict__ bh0,
               const float* __restrict__ wi1, const float* __restrict__ wh1,
               const float* __restrict__ bi1, const float* __restrict__ bh1,
               const float* __restrict__ fcw, const float* __restrict__ fcb,
               float* __restrict__ out, unsigned char* __restrict__ ws)
{
    __shared__ short ldsWi[48 * 512];          // 49152 B, bf16, xor-swizzled rows
    __shared__ short ldsWh[48 * 512];          // 49152 B
    __shared__ float ldsRed[3][64][52];        // 39936 B k-split partials

    const int tid   = threadIdx.x;
    const int lane  = tid & 63;
    const int kq    = tid >> 6;                // wave id = k-quarter
    const int wgid  = blockIdx.x;
    const int layer = wgid >> 7;
    const int wid   = wgid & 127;
    const int mt    = wid & 3;                 // 32-row m-tile
    const int nt    = wid >> 2;                // 16-col hidden tile
    const int l15   = lane & 15;
    const int l4    = lane >> 4;
    const int tile0 = mt * 2;                  // two 16-row fragment tiles

    unsigned* barMast = (unsigned*)(ws + WS_MASTER);
    unsigned short* hbm = (unsigned short*)(ws + WS_HBUF);
    float* h1f = (float*)(ws + WS_H1F);

    unsigned short* h0hi[2] = { hbm + 0 * HBUF_ELEMS, hbm + 1 * HBUF_ELEMS };
    unsigned short* h0lo[2] = { hbm + 2 * HBUF_ELEMS, hbm + 3 * HBUF_ELEMS };
    unsigned short* h1hi[2] = { hbm + 4 * HBUF_ELEMS, hbm + 5 * HBUF_ELEMS };
    unsigned short* h1lo[2] = { hbm + 6 * HBUF_ELEMS, hbm + 7 * HBUF_ELEMS };

    // ---- stage weight slices to LDS (fp32 -> bf16, xor bank swizzle) ----
    {
        const float* Wi = layer ? wi1 : wi0;
        const float* Wh = layer ? wh1 : wh0;
        for (int i = tid; i < 48 * 32; i += WGT) {
            int row = i >> 5, seg = i & 31;
            int jg = (row >> 4) * HID + nt * 16 + (row & 15);   // global gate row
            const float* sa = Wi + (size_t)jg * HID + seg * 16;
            const float* sb = Wh + (size_t)jg * HID + seg * 16;
            int base = row * 1024 + seg * 32;
            int swz  = (row & 7) << 4;
            u16x8 va0, va1, vb0, vb1;
            #pragma unroll
            for (int e = 0; e < 8; ++e) {
                va0[e] = f2bf(sa[e]);     va1[e] = f2bf(sa[8 + e]);
                vb0[e] = f2bf(sb[e]);     vb1[e] = f2bf(sb[8 + e]);
            }
            *(u16x8*)((char*)ldsWi + ((base)      ^ swz)) = va0;
            *(u16x8*)((char*)ldsWi + ((base + 16) ^ swz)) = va1;
            *(u16x8*)((char*)ldsWh + ((base)      ^ swz)) = vb0;
            *(u16x8*)((char*)ldsWh + ((base + 16) ^ swz)) = vb1;
        }
    }

    // ---- per-thread biases (gate-phase threads = wave 0 only) ----
    float br[4] = {0,0,0,0}, bz[4] = {0,0,0,0}, bni[4] = {0,0,0,0}, bnh[4] = {0,0,0,0};
    if (kq == 0) {
        const float* Bi = layer ? bi1 : bi0;
        const float* Bh = layer ? bh1 : bh0;
        int c0 = nt * 16 + (l4 << 2);
        #pragma unroll
        for (int r = 0; r < 4; ++r) {
            int j = c0 + r;
            br[r]  = Bi[j] + Bh[j];
            bz[r]  = Bi[HID + j] + Bh[HID + j];
            bni[r] = Bi[2 * HID + j];
            bnh[r] = Bh[2 * HID + j];
        }
    }

    // W-fragment LDS read bases (row = g*16 + l15, (row&7)==(l15&7))
    int wbase[3];
    #pragma unroll
    for (int g = 0; g < 3; ++g) wbase[g] = (g * 16 + l15) * 1024 + (l4 << 4);
    const int wswz = (l15 & 7) << 4;

    float hold[2][4] = {{0,0,0,0},{0,0,0,0}};  // exact fp32 h_old (wave0)

    __syncthreads();

    for (int s = 0; s <= TS; ++s) {
        const int wp = s & 1, rp = wp ^ 1;
        const bool active = layer ? (s >= 1) : (s < TS);
        if (active) {
            f32x4 acc_i[2][3], acc_h[2][3];
            #pragma unroll
            for (int m2 = 0; m2 < 2; ++m2)
                #pragma unroll
                for (int g = 0; g < 3; ++g) {
                    acc_i[m2][g] = (f32x4){0.f,0.f,0.f,0.f};
                    acc_h[m2][g] = (f32x4){0.f,0.f,0.f,0.f};
                }

            const unsigned short* pIhi = layer ? h0hi[rp] : (const unsigned short*)0;
            const unsigned short* pIlo = layer ? h0lo[rp] : (const unsigned short*)0;
            const unsigned short* pHhi = layer ? h1hi[rp] : h0hi[rp];
            const unsigned short* pHlo = layer ? h1lo[rp] : h0lo[rp];

            #pragma unroll
            for (int kk = 0; kk < 4; ++kk) {
                const int kc = (kq << 2) + kk;          // k-chunk of 32
                #pragma unroll
                for (int m2 = 0; m2 < 2; ++m2) {
                    const int tile = tile0 + m2;
                    const int fo = (((tile * 16 + kc) * 64) + lane) * 8;
                    bf16x8 vIhi, vIlo;
                    if (layer == 0) {
                        // direct fp32 x load, split hi/lo in registers
                        const int m = tile * 16 + l15;
                        const int k = kc * 32 + (l4 << 3);
                        const float* xp = x + ((size_t)m * TS + s) * HID + k;
                        f32x4 xa = *(const f32x4*)xp;
                        f32x4 xb = *(const f32x4*)(xp + 4);
                        #pragma unroll
                        for (int e = 0; e < 4; ++e) {
                            unsigned short h1b = f2bf(xa[e]);
                            vIhi[e] = (short)h1b;
                            vIlo[e] = (short)f2bf(xa[e] - bf2f(h1b));
                            unsigned short h2b = f2bf(xb[e]);
                            vIhi[4 + e] = (short)h2b;
                            vIlo[4 + e] = (short)f2bf(xb[e] - bf2f(h2b));
                        }
                    } else {
                        vIhi = *(const bf16x8*)(pIhi + fo);
                        vIlo = *(const bf16x8*)(pIlo + fo);
                    }
                    bf16x8 vHhi = *(const bf16x8*)(pHhi + fo);
                    bf16x8 vHlo = *(const bf16x8*)(pHlo + fo);
                    #pragma unroll
                    for (int g = 0; g < 3; ++g) {
                        const int wo = wbase[g] + kc * 64;
                        bf16x8 wiF = *(const bf16x8*)((const char*)ldsWi + (wo ^ wswz));
                        bf16x8 whF = *(const bf16x8*)((const char*)ldsWh + (wo ^ wswz));
                        acc_i[m2][g] = __builtin_amdgcn_mfma_f32_16x16x32_bf16(wiF, vIlo, acc_i[m2][g], 0, 0, 0);
                        acc_i[m2][g] = __builtin_amdgcn_mfma_f32_16x16x32_bf16(wiF, vIhi, acc_i[m2][g], 0, 0, 0);
                        acc_h[m2][g] = __builtin_amdgcn_mfma_f32_16x16x32_bf16(whF, vHlo, acc_h[m2][g], 0, 0, 0);
                        acc_h[m2][g] = __builtin_amdgcn_mfma_f32_16x16x32_bf16(whF, vHhi, acc_h[m2][g], 0, 0, 0);
                    }
                }
            }

            // ---- k-split reduction ----
            if (kq != 0) {
                float* p = &ldsRed[kq - 1][lane][0];
                #pragma unroll
                for (int m2 = 0; m2 < 2; ++m2)
                    #pragma unroll
                    for (int g = 0; g < 3; ++g) {
                        *(f32x4*)(p + m2 * 24 + g * 4)      = acc_i[m2][g];
                        *(f32x4*)(p + m2 * 24 + 12 + g * 4) = acc_h[m2][g];
                    }
            }
            __syncthreads();
            if (kq == 0) {
                #pragma unroll
                for (int q = 0; q < 3; ++q) {
                    const float* p = &ldsRed[q][lane][0];
                    #pragma unroll
                    for (int m2 = 0; m2 < 2; ++m2)
                        #pragma unroll
                        for (int g = 0; g < 3; ++g) {
                            acc_i[m2][g] += *(const f32x4*)(p + m2 * 24 + g * 4);
                            acc_h[m2][g] += *(const f32x4*)(p + m2 * 24 + 12 + g * 4);
                        }
                }
                // ---- gates (fp32) + fragment-layout hi/lo store ----
                unsigned short* dsthi = layer ? h1hi[wp] : h0hi[wp];
                unsigned short* dstlo = layer ? h1lo[wp] : h0lo[wp];
                const int klocal0 = ((nt & 1) << 4) + (l4 << 2);
                const int lanep = l15 | ((klocal0 >> 3) << 4);
                const int chunk = nt >> 1;
                #pragma unroll
                for (int m2 = 0; m2 < 2; ++m2) {
                    u16x4 shi, slo; f32x4 hv;
                    #pragma unroll
                    for (int r = 0; r < 4; ++r) {
                        float vr = acc_i[m2][0][r] + acc_h[m2][0][r] + br[r];
                        float vz = acc_i[m2][1][r] + acc_h[m2][1][r] + bz[r];
                        float rg = sigm(vr);
                        float zg = sigm(vz);
                        float ng = tanh_(acc_i[m2][2][r] + bni[r] + rg * (acc_h[m2][2][r] + bnh[r]));
                        float h  = (1.0f - zg) * ng + zg * hold[m2][r];
                        hold[m2][r] = h;
                        hv[r] = h;
                        unsigned short hb = f2bf(h);
                        shi[r] = hb;
                        slo[r] = f2bf(h - bf2f(hb));
                    }
                    const int eo = ((((tile0 + m2) * 16 + chunk) * 64) + lanep) * 8 + (klocal0 & 7);
                    *(u16x4*)(dsthi + eo) = shi;
                    *(u16x4*)(dstlo + eo) = slo;
                    if (layer && s == TS) {          // exact fp32 copy for FC
                        const int m = (tile0 + m2) * 16 + l15;
                        const int kg0 = nt * 16 + (l4 << 2);
                        *(f32x4*)(h1f + (size_t)m * HID + kg0) = hv;
                    }
                }
            }
        }

        // ---- grid barrier (2-level, monotonic counters) ----
        if (active && kq == 0) __threadfence();   // flush h stores to device scope
        __syncthreads();
        if (tid == 0) {
            unsigned* leaf = (unsigned*)(ws + (size_t)(wgid & 15) * 64);
            unsigned old = __hip_atomic_fetch_add(leaf, 1u, __ATOMIC_RELEASE, __HIP_MEMORY_SCOPE_AGENT);
            if (old == (unsigned)(s * 16 + 15))
                __hip_atomic_fetch_add(barMast, 1u, __ATOMIC_RELEASE, __HIP_MEMORY_SCOPE_AGENT);
            const unsigned tgt = (unsigned)((s + 1) * 16);
            while (__hip_atomic_load(barMast, __ATOMIC_RELAXED, __HIP_MEMORY_SCOPE_AGENT) < tgt)
                __builtin_amdgcn_s_sleep(2);
            __threadfence();                      // acquire: invalidate stale caches
        }
        __syncthreads();
    }

    // ---- FC epilogue: out = h1f @ fc_w^T + fc_b (fp32, layer-0 wgs) ----
    if (wgid < 64) {
        float* fw = (float*)ldsWi;                // reuse LDS, rows padded to 516
        const float* src = fcw + (size_t)wgid * 8 * HID;
        for (int i = tid; i < (8 * HID) / 4; i += WGT) {
            f32x4 v = *(const f32x4*)(src + i * 4);
            int row = (i * 4) >> 9;
            int kk  = (i * 4) & 511;
            *(f32x4*)(fw + row * 516 + kk) = v;
        }
        __syncthreads();
        const int col = wgid * 8 + (tid & 7);
        const int m0  = tid >> 3;                 // 0..31
        float a0 = fcb[col], a1 = a0, a2 = a0, a3 = a0;
        const float* fwr = fw + (tid & 7) * 516;
        for (int k = 0; k < HID; k += 4) {
            f32x4 wv  = *(const f32x4*)(fwr + k);
            f32x4 h0v = *(const f32x4*)(h1f + (size_t)(m0)      * HID + k);
            f32x4 h1v = *(const f32x4*)(h1f + (size_t)(m0 + 32) * HID + k);
            f32x4 h2v = *(const f32x4*)(h1f + (size_t)(m0 + 64) * HID + k);
            f32x4 h3v = *(const f32x4*)(h1f + (size_t)(m0 + 96) * HID + k);
            a0 += h0v[0]*wv[0] + h0v[1]*wv[1] + h0v[2]*wv[2] + h0v[3]*wv[3];
            a1 += h1v[0]*wv[0] + h1v[1]*wv[1] + h1v[2]*wv[2] + h1v[3]*wv[3];
            a2 += h2v[0]*wv[0] + h2v[1]*wv[1] + h2v[2]*wv[2] + h2v[3]*wv[3];
            a3 += h3v[0]*wv[0] + h3v[1]*wv[1] + h3v[2]*wv[2] + h3v[3]*wv[3];
        }
        out[(size_t)(m0)      * HID + col] = a0;
        out[(size_t)(m0 + 32) * HID + col] = a1;
        out[(size_t)(m0 + 64) * HID + col] = a2;
        out[(size_t)(m0 + 96) * HID + col] = a3;
    }
}

extern "C" void kernel_launch(void* const* d_in, const int* in_sizes, int n_in,
                              void* d_out, int out_size, void* d_ws, size_t ws_size,
                              hipStream_t stream) {
    (void)in_sizes; (void)n_in; (void)out_size; (void)ws_size;
    // zero barrier counters + hidden-state double buffers (h(-1) = 0)
    hipMemsetAsync(d_ws, 0, WS_ZERO, stream);
    gru_persistent<<<dim3(NWG), dim3(WGT), 0, stream>>>(
        (const float*)d_in[0],
        (const float*)d_in[1], (const float*)d_in[2],
        (const float*)d_in[3], (const float*)d_in[4],
        (const float*)d_in[5], (const float*)d_in[6],
        (const float*)d_in[7], (const float*)d_in[8],
        (const float*)d_in[9], (const float*)d_in[10],
        (float*)d_out, (unsigned char*)d_ws);
}

// Round 2
// 14838.388 us; speedup vs baseline: 1.5993x; 1.5993x over previous
//
#include <hip/hip_runtime.h>

// ---------------------------------------------------------------------------
// Persistent 2-layer GRU for MI355X (gfx950).  B=128, T=1024, D=H=512.
// 256 wgs x 256 thr, 1 wg/CU. wg = (layer, mt, nt): 32 batch rows x 16 hid cols.
// Waves k-split K=512 into 4x128; weights live in REGISTERS (24 bf16x8 frags
// per matrix per wave). LDS only holds the k-split reduce buffer.
// Cross-wg h handoff: write-through (sc0 sc1) stores to LLC + relaxed agent
// atomics + one buffer_inv sc1 per interval. NO threadfence (no wbl2 storm).
// Layer-0's x-GEMM for step s+1 runs inside the barrier window.
// ---------------------------------------------------------------------------

#define TS   1024
#define HID  512
#define NWG  256
#define WGT  256

typedef __attribute__((ext_vector_type(8))) short bf16x8;
typedef __attribute__((ext_vector_type(4))) unsigned short u16x4;
typedef __attribute__((ext_vector_type(4))) float f32x4;

#define WS_MASTER   4096
#define WS_HBUF     8192
#define HBUF_ELEMS  65536                             // 128*512 bf16 per buffer
#define WS_H1F      (WS_HBUF + 8 * HBUF_ELEMS * 2)    // fp32 [128][512]
#define WS_ZERO     (WS_HBUF + 8 * HBUF_ELEMS * 2)

__device__ __forceinline__ unsigned short f2bf(float f) {
    unsigned u = __float_as_uint(f);
    u += 0x7FFFu + ((u >> 16) & 1u);
    return (unsigned short)(u >> 16);
}
__device__ __forceinline__ float bf2f(unsigned short s) {
    return __uint_as_float(((unsigned)s) << 16);
}
__device__ __forceinline__ float sigm(float v) { return 1.0f / (1.0f + __expf(-v)); }
__device__ __forceinline__ float tanh_(float v) { return 1.0f - 2.0f / (1.0f + __expf(2.0f * v)); }

// write-through to LLC (device coherence point) — bypasses dirty-L2 state
__device__ __forceinline__ void st_llc8(void* p, unsigned long long v) {
    asm volatile("global_store_dwordx2 %0, %1, off sc0 sc1" :: "v"(p), "v"(v) : "memory");
}
__device__ __forceinline__ void st_llc16(void* p, f32x4 v) {
    asm volatile("global_store_dwordx4 %0, %1, off sc0 sc1" :: "v"(p), "v"(v) : "memory");
}

__global__ void __launch_bounds__(WGT, 1)
gru_persistent(const float* __restrict__ x,
               const float* __restrict__ wi0, const float* __restrict__ wh0,
               const float* __restrict__ bi0, const float* __restrict__ bh0,
               const float* __restrict__ wi1, const float* __restrict__ wh1,
               const float* __restrict__ bi1, const float* __restrict__ bh1,
               const float* __restrict__ fcw, const float* __restrict__ fcb,
               float* __restrict__ out, unsigned char* __restrict__ ws)
{
    __shared__ float ldsRed[3][64][52];        // 39936 B k-split partials

    const int tid   = threadIdx.x;
    const int lane  = tid & 63;
    const int kq    = tid >> 6;                // wave id = k-quarter
    const int wgid  = blockIdx.x;
    const int layer = wgid >> 7;
    const int wid   = wgid & 127;
    const int mt    = wid & 3;                 // 32-row m-tile
    const int nt    = wid >> 2;                // 16-col hidden tile
    const int l15   = lane & 15;
    const int l4    = lane >> 4;
    const int tile0 = mt * 2;

    unsigned* barMast = (unsigned*)(ws + WS_MASTER);
    unsigned* leaf    = (unsigned*)(ws + (size_t)(wgid & 15) * 64);
    unsigned short* hbm = (unsigned short*)(ws + WS_HBUF);
    float* h1f = (float*)(ws + WS_H1F);

    unsigned short* h0hi[2] = { hbm + 0 * HBUF_ELEMS, hbm + 1 * HBUF_ELEMS };
    unsigned short* h0lo[2] = { hbm + 2 * HBUF_ELEMS, hbm + 3 * HBUF_ELEMS };
    unsigned short* h1hi[2] = { hbm + 4 * HBUF_ELEMS, hbm + 5 * HBUF_ELEMS };
    unsigned short* h1lo[2] = { hbm + 6 * HBUF_ELEMS, hbm + 7 * HBUF_ELEMS };

    // ---- stage weight fragments into REGISTERS (fp32 -> bf16) ----
    bf16x8 wiR[4][3], whR[4][3];
    {
        const float* Wi = layer ? wi1 : wi0;
        const float* Wh = layer ? wh1 : wh0;
        #pragma unroll
        for (int kk = 0; kk < 4; ++kk) {
            const int kc = (kq << 2) + kk;
            #pragma unroll
            for (int g = 0; g < 3; ++g) {
                const int jg = g * HID + nt * 16 + l15;
                const float* pi = Wi + (size_t)jg * HID + kc * 32 + (l4 << 3);
                const float* ph = Wh + (size_t)jg * HID + kc * 32 + (l4 << 3);
                #pragma unroll
                for (int e = 0; e < 8; ++e) {
                    wiR[kk][g][e] = (short)f2bf(pi[e]);
                    whR[kk][g][e] = (short)f2bf(ph[e]);
                }
            }
        }
    }

    // ---- per-thread biases (wave 0 only) ----
    float br[4] = {0,0,0,0}, bz[4] = {0,0,0,0}, bni[4] = {0,0,0,0}, bnh[4] = {0,0,0,0};
    if (kq == 0) {
        const float* Bi = layer ? bi1 : bi0;
        const float* Bh = layer ? bh1 : bh0;
        int c0 = nt * 16 + (l4 << 2);
        #pragma unroll
        for (int r = 0; r < 4; ++r) {
            int j = c0 + r;
            br[r]  = Bi[j] + Bh[j];
            bz[r]  = Bi[HID + j] + Bh[HID + j];
            bni[r] = Bi[2 * HID + j];
            bnh[r] = Bh[2 * HID + j];
        }
    }

    float hold[2][4] = {{0,0,0,0},{0,0,0,0}};
    f32x4 acc_i[2][3], acc_h[2][3];
    #pragma unroll
    for (int m2 = 0; m2 < 2; ++m2)
        #pragma unroll
        for (int g = 0; g < 3; ++g) {
            acc_i[m2][g] = (f32x4){0.f,0.f,0.f,0.f};
            acc_h[m2][g] = (f32x4){0.f,0.f,0.f,0.f};
        }

    // layer-0 x-side GEMM for step sn (h-independent, runs in barrier window)
    auto l0_input_mfma = [&](int sn) {
        #pragma unroll
        for (int kk = 0; kk < 4; ++kk) {
            const int kc = (kq << 2) + kk;
            #pragma unroll
            for (int m2 = 0; m2 < 2; ++m2) {
                const int m = (tile0 + m2) * 16 + l15;
                const int k = kc * 32 + (l4 << 3);
                const float* xp = x + ((size_t)m * TS + sn) * HID + k;
                f32x4 xa = *(const f32x4*)xp;
                f32x4 xb = *(const f32x4*)(xp + 4);
                bf16x8 vIhi, vIlo;
                #pragma unroll
                for (int e = 0; e < 4; ++e) {
                    unsigned short h1b = f2bf(xa[e]);
                    vIhi[e] = (short)h1b;
                    vIlo[e] = (short)f2bf(xa[e] - bf2f(h1b));
                    unsigned short h2b = f2bf(xb[e]);
                    vIhi[4 + e] = (short)h2b;
                    vIlo[4 + e] = (short)f2bf(xb[e] - bf2f(h2b));
                }
                #pragma unroll
                for (int g = 0; g < 3; ++g) {
                    acc_i[m2][g] = __builtin_amdgcn_mfma_f32_16x16x32_bf16(wiR[kk][g], vIlo, acc_i[m2][g], 0, 0, 0);
                    acc_i[m2][g] = __builtin_amdgcn_mfma_f32_16x16x32_bf16(wiR[kk][g], vIhi, acc_i[m2][g], 0, 0, 0);
                }
            }
        }
    };

    __syncthreads();
    if (layer == 0) l0_input_mfma(0);          // prologue: acc_i for step 0

    for (int s = 0; s <= TS; ++s) {
        const int wp = s & 1, rp = wp ^ 1;
        const bool active = layer ? (s >= 1) : (s < TS);
        if (active) {
            #pragma unroll
            for (int m2 = 0; m2 < 2; ++m2)
                #pragma unroll
                for (int g = 0; g < 3; ++g) {
                    acc_h[m2][g] = (f32x4){0.f,0.f,0.f,0.f};
                    if (layer) acc_i[m2][g] = (f32x4){0.f,0.f,0.f,0.f};
                }

            const unsigned short* pIhi = h0hi[rp];
            const unsigned short* pIlo = h0lo[rp];
            const unsigned short* pHhi = layer ? h1hi[rp] : h0hi[rp];
            const unsigned short* pHlo = layer ? h1lo[rp] : h0lo[rp];

            #pragma unroll
            for (int kk = 0; kk < 4; ++kk) {
                const int kc = (kq << 2) + kk;
                #pragma unroll
                for (int m2 = 0; m2 < 2; ++m2) {
                    const int fo = ((((tile0 + m2) * 16 + kc) * 64) + lane) * 8;
                    bf16x8 vHhi = *(const bf16x8*)(pHhi + fo);
                    bf16x8 vHlo = *(const bf16x8*)(pHlo + fo);
                    if (layer) {
                        bf16x8 vIhi = *(const bf16x8*)(pIhi + fo);
                        bf16x8 vIlo = *(const bf16x8*)(pIlo + fo);
                        #pragma unroll
                        for (int g = 0; g < 3; ++g) {
                            acc_i[m2][g] = __builtin_amdgcn_mfma_f32_16x16x32_bf16(wiR[kk][g], vIlo, acc_i[m2][g], 0, 0, 0);
                            acc_i[m2][g] = __builtin_amdgcn_mfma_f32_16x16x32_bf16(wiR[kk][g], vIhi, acc_i[m2][g], 0, 0, 0);
                        }
                    }
                    #pragma unroll
                    for (int g = 0; g < 3; ++g) {
                        acc_h[m2][g] = __builtin_amdgcn_mfma_f32_16x16x32_bf16(whR[kk][g], vHlo, acc_h[m2][g], 0, 0, 0);
                        acc_h[m2][g] = __builtin_amdgcn_mfma_f32_16x16x32_bf16(whR[kk][g], vHhi, acc_h[m2][g], 0, 0, 0);
                    }
                }
            }

            if (kq != 0) {
                float* p = &ldsRed[kq - 1][lane][0];
                #pragma unroll
                for (int m2 = 0; m2 < 2; ++m2)
                    #pragma unroll
                    for (int g = 0; g < 3; ++g) {
                        *(f32x4*)(p + m2 * 24 + g * 4)      = acc_i[m2][g];
                        *(f32x4*)(p + m2 * 24 + 12 + g * 4) = acc_h[m2][g];
                    }
            }
            __syncthreads();                   // (A)
            if (kq == 0) {
                #pragma unroll
                for (int q = 0; q < 3; ++q) {
                    const float* p = &ldsRed[q][lane][0];
                    #pragma unroll
                    for (int m2 = 0; m2 < 2; ++m2)
                        #pragma unroll
                        for (int g = 0; g < 3; ++g) {
                            acc_i[m2][g] += *(const f32x4*)(p + m2 * 24 + g * 4);
                            acc_h[m2][g] += *(const f32x4*)(p + m2 * 24 + 12 + g * 4);
                        }
                }
                unsigned short* dsthi = layer ? h1hi[wp] : h0hi[wp];
                unsigned short* dstlo = layer ? h1lo[wp] : h0lo[wp];
                const int klocal0 = ((nt & 1) << 4) + (l4 << 2);
                const int lanep = l15 | ((klocal0 >> 3) << 4);
                const int chunk = nt >> 1;
                #pragma unroll
                for (int m2 = 0; m2 < 2; ++m2) {
                    u16x4 shi, slo; f32x4 hv;
                    #pragma unroll
                    for (int r = 0; r < 4; ++r) {
                        float vr = acc_i[m2][0][r] + acc_h[m2][0][r] + br[r];
                        float vz = acc_i[m2][1][r] + acc_h[m2][1][r] + bz[r];
                        float rg = sigm(vr);
                        float zg = sigm(vz);
                        float ng = tanh_(acc_i[m2][2][r] + bni[r] + rg * (acc_h[m2][2][r] + bnh[r]));
                        float h  = (1.0f - zg) * ng + zg * hold[m2][r];
                        hold[m2][r] = h;
                        hv[r] = h;
                        unsigned short hb = f2bf(h);
                        shi[r] = hb;
                        slo[r] = f2bf(h - bf2f(hb));
                    }
                    const int eo = ((((tile0 + m2) * 16 + chunk) * 64) + lanep) * 8 + (klocal0 & 7);
                    st_llc8(dsthi + eo, __builtin_bit_cast(unsigned long long, shi));
                    st_llc8(dstlo + eo, __builtin_bit_cast(unsigned long long, slo));
                    if (layer && s == TS) {
                        const int m = (tile0 + m2) * 16 + l15;
                        const int kg0 = nt * 16 + (l4 << 2);
                        st_llc16(h1f + (size_t)m * HID + kg0, hv);
                    }
                }
            }
        }

        // ---- arrive (release: stores ACKed at LLC before leaf add) ----
        if (tid == 0) {
            asm volatile("s_waitcnt vmcnt(0)" ::: "memory");
            unsigned old = __hip_atomic_fetch_add(leaf, 1u, __ATOMIC_RELAXED, __HIP_MEMORY_SCOPE_AGENT);
            if (old == (unsigned)(s * 16 + 15))
                __hip_atomic_fetch_add(barMast, 1u, __ATOMIC_RELAXED, __HIP_MEMORY_SCOPE_AGENT);
        }

        // ---- barrier window: layer-0 computes next step's x-GEMM ----
        if (layer == 0 && s + 1 < TS) {
            #pragma unroll
            for (int m2 = 0; m2 < 2; ++m2)
                #pragma unroll
                for (int g = 0; g < 3; ++g)
                    acc_i[m2][g] = (f32x4){0.f,0.f,0.f,0.f};
            l0_input_mfma(s + 1);
        }

        // ---- spin + acquire ----
        if (tid == 0) {
            const unsigned tgt = (unsigned)((s + 1) * 16);
            while (__hip_atomic_load(barMast, __ATOMIC_RELAXED, __HIP_MEMORY_SCOPE_AGENT) < tgt)
                __builtin_amdgcn_s_sleep(1);
        }
        asm volatile("buffer_inv sc1" ::: "memory");   // invalidate stale L1/L2
        __syncthreads();                   // (B)
    }

    // ---- FC epilogue: out = h1f @ fc_w^T + fc_b (layer-0 wgs, fp32) ----
    if (wgid < 64) {
        float* fw = (float*)ldsRed;               // 8 rows x 516 floats
        const float* src = fcw + (size_t)wgid * 8 * HID;
        for (int i = tid; i < (8 * HID) / 4; i += WGT) {
            f32x4 v = *(const f32x4*)(src + i * 4);
            int row = (i * 4) >> 9;
            int kk  = (i * 4) & 511;
            *(f32x4*)(fw + row * 516 + kk) = v;
        }
        __syncthreads();
        const int col = wgid * 8 + (tid & 7);
        const int m0  = tid >> 3;
        float a0 = fcb[col], a1 = a0, a2 = a0, a3 = a0;
        const float* fwr = fw + (tid & 7) * 516;
        for (int k = 0; k < HID; k += 4) {
            f32x4 wv  = *(const f32x4*)(fwr + k);
            f32x4 h0v = *(const f32x4*)(h1f + (size_t)(m0)      * HID + k);
            f32x4 h1v = *(const f32x4*)(h1f + (size_t)(m0 + 32) * HID + k);
            f32x4 h2v = *(const f32x4*)(h1f + (size_t)(m0 + 64) * HID + k);
            f32x4 h3v = *(const f32x4*)(h1f + (size_t)(m0 + 96) * HID + k);
            a0 += h0v[0]*wv[0] + h0v[1]*wv[1] + h0v[2]*wv[2] + h0v[3]*wv[3];
            a1 += h1v[0]*wv[0] + h1v[1]*wv[1] + h1v[2]*wv[2] + h1v[3]*wv[3];
            a2 += h2v[0]*wv[0] + h2v[1]*wv[1] + h2v[2]*wv[2] + h2v[3]*wv[3];
            a3 += h3v[0]*wv[0] + h3v[1]*wv[1] + h3v[2]*wv[2] + h3v[3]*wv[3];
        }
        out[(size_t)(m0)      * HID + col] = a0;
        out[(size_t)(m0 + 32) * HID + col] = a1;
        out[(size_t)(m0 + 64) * HID + col] = a2;
        out[(size_t)(m0 + 96) * HID + col] = a3;
    }
}

extern "C" void kernel_launch(void* const* d_in, const int* in_sizes, int n_in,
                              void* d_out, int out_size, void* d_ws, size_t ws_size,
                              hipStream_t stream) {
    (void)in_sizes; (void)n_in; (void)out_size; (void)ws_size;
    hipMemsetAsync(d_ws, 0, WS_ZERO, stream);
    gru_persistent<<<dim3(NWG), dim3(WGT), 0, stream>>>(
        (const float*)d_in[0],
        (const float*)d_in[1], (const float*)d_in[2],
        (const float*)d_in[3], (const float*)d_in[4],
        (const float*)d_in[5], (const float*)d_in[6],
        (const float*)d_in[7], (const float*)d_in[8],
        (const float*)d_in[9], (const float*)d_in[10],
        (float*)d_out, (unsigned char*)d_ws);
}

// Round 3
// 9235.853 us; speedup vs baseline: 2.5694x; 1.6066x over previous
//
#include <hip/hip_runtime.h>

// ---------------------------------------------------------------------------
// Persistent 2-layer GRU for MI355X (gfx950).  B=128, T=1024, D=H=512.
// 256 wgs x 256 thr, 1 wg/CU. wg = (layer, mt, nt): 32 batch rows x 16 hid cols.
// Waves k-split K=512 into 4x128; weights in REGISTERS (24 bf16x8 frags/matrix).
// ZERO cache-maintenance ops: h handoff uses write-through (sc0 sc1) stores +
// agent-scope relaxed atomic loads (sc0 sc1, bypass L1/L2, read LLC directly).
// x/weights use normal cached loads on a never-invalidated L2.
// Barrier: 4 independent per-mt groups (64 wgs each, 8x8 leaf/master tree),
// one barrier per interval; global fin counter gates the FC epilogue.
// Layer-0's x-GEMM for step s+1 runs inside the barrier window.
// ---------------------------------------------------------------------------

#define TS   1024
#define HID  512
#define NWG  256
#define WGT  256

typedef __attribute__((ext_vector_type(8))) short bf16x8;
typedef __attribute__((ext_vector_type(4))) unsigned short u16x4;
typedef __attribute__((ext_vector_type(4))) float f32x4;

#define WS_HBUF     8192
#define HBUF_ELEMS  65536                             // 128*512 bf16 per buffer
#define WS_H1F      (WS_HBUF + 8 * HBUF_ELEMS * 2)    // fp32 [128][512]
#define WS_ZERO     (WS_HBUF + 8 * HBUF_ELEMS * 2)

__device__ __forceinline__ unsigned short f2bf(float f) {
    unsigned u = __float_as_uint(f);
    u += 0x7FFFu + ((u >> 16) & 1u);
    return (unsigned short)(u >> 16);
}
__device__ __forceinline__ float bf2f(unsigned short s) {
    return __uint_as_float(((unsigned)s) << 16);
}
__device__ __forceinline__ float sigm(float v) { return 1.0f / (1.0f + __expf(-v)); }
__device__ __forceinline__ float tanh_(float v) { return 1.0f - 2.0f / (1.0f + __expf(2.0f * v)); }

// write-through to LLC (device coherence point)
__device__ __forceinline__ void st_llc8(void* p, unsigned long long v) {
    asm volatile("global_store_dwordx2 %0, %1, off sc0 sc1" :: "v"(p), "v"(v) : "memory");
}
__device__ __forceinline__ void st_llc16(void* p, f32x4 v) {
    asm volatile("global_store_dwordx4 %0, %1, off sc0 sc1" :: "v"(p), "v"(v) : "memory");
}
// coherent 16B load (2x agent-scope relaxed u64 atomic loads -> sc0 sc1)
__device__ __forceinline__ bf16x8 ld_coh16(const unsigned short* p) {
    const unsigned long long* q = (const unsigned long long*)p;
    union { unsigned long long u[2]; bf16x8 v; } r;
    r.u[0] = __hip_atomic_load(q,     __ATOMIC_RELAXED, __HIP_MEMORY_SCOPE_AGENT);
    r.u[1] = __hip_atomic_load(q + 1, __ATOMIC_RELAXED, __HIP_MEMORY_SCOPE_AGENT);
    return r.v;
}
__device__ __forceinline__ f32x4 ld_coh16f(const float* p) {
    const unsigned long long* q = (const unsigned long long*)p;
    union { unsigned long long u[2]; f32x4 v; } r;
    r.u[0] = __hip_atomic_load(q,     __ATOMIC_RELAXED, __HIP_MEMORY_SCOPE_AGENT);
    r.u[1] = __hip_atomic_load(q + 1, __ATOMIC_RELAXED, __HIP_MEMORY_SCOPE_AGENT);
    return r.v;
}

__global__ void __launch_bounds__(WGT, 1)
gru_persistent(const float* __restrict__ x,
               const float* __restrict__ wi0, const float* __restrict__ wh0,
               const float* __restrict__ bi0, const float* __restrict__ bh0,
               const float* __restrict__ wi1, const float* __restrict__ wh1,
               const float* __restrict__ bi1, const float* __restrict__ bh1,
               const float* __restrict__ fcw, const float* __restrict__ fcb,
               float* __restrict__ out, unsigned char* __restrict__ ws)
{
    __shared__ float ldsRed[3][64][52];        // 39936 B k-split partials

    const int tid   = threadIdx.x;
    const int lane  = tid & 63;
    const int kq    = tid >> 6;                // wave id = k-quarter
    const int wgid  = blockIdx.x;
    const int layer = wgid >> 7;
    const int wid   = wgid & 127;
    const int mt    = wid & 3;                 // 32-row m-tile (barrier group)
    const int nt    = wid >> 2;                // 16-col hidden tile
    const int l15   = lane & 15;
    const int l4    = lane >> 4;
    const int tile0 = mt * 2;
    const int gidx  = layer * 32 + nt;         // 0..63 within mt-group

    unsigned* leaf   = (unsigned*)(ws + (size_t)(mt * 8 + (gidx >> 3)) * 64);
    unsigned* master = (unsigned*)(ws + 2048 + (size_t)mt * 64);
    unsigned* fin    = (unsigned*)(ws + 2560);
    unsigned short* hbm = (unsigned short*)(ws + WS_HBUF);
    float* h1f = (float*)(ws + WS_H1F);

    unsigned short* h0hi[2] = { hbm + 0 * HBUF_ELEMS, hbm + 1 * HBUF_ELEMS };
    unsigned short* h0lo[2] = { hbm + 2 * HBUF_ELEMS, hbm + 3 * HBUF_ELEMS };
    unsigned short* h1hi[2] = { hbm + 4 * HBUF_ELEMS, hbm + 5 * HBUF_ELEMS };
    unsigned short* h1lo[2] = { hbm + 6 * HBUF_ELEMS, hbm + 7 * HBUF_ELEMS };

    // ---- stage weight fragments into REGISTERS (fp32 -> bf16) ----
    bf16x8 wiR[4][3], whR[4][3];
    {
        const float* Wi = layer ? wi1 : wi0;
        const float* Wh = layer ? wh1 : wh0;
        #pragma unroll
        for (int kk = 0; kk < 4; ++kk) {
            const int kc = (kq << 2) + kk;
            #pragma unroll
            for (int g = 0; g < 3; ++g) {
                const int jg = g * HID + nt * 16 + l15;
                const float* pi = Wi + (size_t)jg * HID + kc * 32 + (l4 << 3);
                const float* ph = Wh + (size_t)jg * HID + kc * 32 + (l4 << 3);
                #pragma unroll
                for (int e = 0; e < 8; ++e) {
                    wiR[kk][g][e] = (short)f2bf(pi[e]);
                    whR[kk][g][e] = (short)f2bf(ph[e]);
                }
            }
        }
    }

    // ---- per-thread biases (wave 0 only) ----
    float br[4] = {0,0,0,0}, bz[4] = {0,0,0,0}, bni[4] = {0,0,0,0}, bnh[4] = {0,0,0,0};
    if (kq == 0) {
        const float* Bi = layer ? bi1 : bi0;
        const float* Bh = layer ? bh1 : bh0;
        int c0 = nt * 16 + (l4 << 2);
        #pragma unroll
        for (int r = 0; r < 4; ++r) {
            int j = c0 + r;
            br[r]  = Bi[j] + Bh[j];
            bz[r]  = Bi[HID + j] + Bh[HID + j];
            bni[r] = Bi[2 * HID + j];
            bnh[r] = Bh[2 * HID + j];
        }
    }

    float hold[2][4] = {{0,0,0,0},{0,0,0,0}};
    f32x4 acc_i[2][3], acc_h[2][3];
    #pragma unroll
    for (int m2 = 0; m2 < 2; ++m2)
        #pragma unroll
        for (int g = 0; g < 3; ++g) {
            acc_i[m2][g] = (f32x4){0.f,0.f,0.f,0.f};
            acc_h[m2][g] = (f32x4){0.f,0.f,0.f,0.f};
        }

    // layer-0 x-side GEMM for step sn (h-independent, runs in barrier window)
    auto l0_input_mfma = [&](int sn) {
        #pragma unroll
        for (int kk = 0; kk < 4; ++kk) {
            const int kc = (kq << 2) + kk;
            #pragma unroll
            for (int m2 = 0; m2 < 2; ++m2) {
                const int m = (tile0 + m2) * 16 + l15;
                const int k = kc * 32 + (l4 << 3);
                const float* xp = x + ((size_t)m * TS + sn) * HID + k;
                f32x4 xa = *(const f32x4*)xp;
                f32x4 xb = *(const f32x4*)(xp + 4);
                bf16x8 vIhi, vIlo;
                #pragma unroll
                for (int e = 0; e < 4; ++e) {
                    unsigned short h1b = f2bf(xa[e]);
                    vIhi[e] = (short)h1b;
                    vIlo[e] = (short)f2bf(xa[e] - bf2f(h1b));
                    unsigned short h2b = f2bf(xb[e]);
                    vIhi[4 + e] = (short)h2b;
                    vIlo[4 + e] = (short)f2bf(xb[e] - bf2f(h2b));
                }
                #pragma unroll
                for (int g = 0; g < 3; ++g) {
                    acc_i[m2][g] = __builtin_amdgcn_mfma_f32_16x16x32_bf16(wiR[kk][g], vIlo, acc_i[m2][g], 0, 0, 0);
                    acc_i[m2][g] = __builtin_amdgcn_mfma_f32_16x16x32_bf16(wiR[kk][g], vIhi, acc_i[m2][g], 0, 0, 0);
                }
            }
        }
    };

    __syncthreads();
    if (layer == 0) l0_input_mfma(0);          // prologue: acc_i for step 0

    for (int s = 0; s <= TS; ++s) {
        const int wp = s & 1, rp = wp ^ 1;
        const bool active = layer ? (s >= 1) : (s < TS);
        if (active) {
            #pragma unroll
            for (int m2 = 0; m2 < 2; ++m2)
                #pragma unroll
                for (int g = 0; g < 3; ++g) {
                    acc_h[m2][g] = (f32x4){0.f,0.f,0.f,0.f};
                    if (layer) acc_i[m2][g] = (f32x4){0.f,0.f,0.f,0.f};
                }

            const unsigned short* pIhi = h0hi[rp];
            const unsigned short* pIlo = h0lo[rp];
            const unsigned short* pHhi = layer ? h1hi[rp] : h0hi[rp];
            const unsigned short* pHlo = layer ? h1lo[rp] : h0lo[rp];

            #pragma unroll
            for (int kk = 0; kk < 4; ++kk) {
                const int kc = (kq << 2) + kk;
                #pragma unroll
                for (int m2 = 0; m2 < 2; ++m2) {
                    const int fo = ((((tile0 + m2) * 16 + kc) * 64) + lane) * 8;
                    bf16x8 vHhi = ld_coh16(pHhi + fo);
                    bf16x8 vHlo = ld_coh16(pHlo + fo);
                    if (layer) {
                        bf16x8 vIhi = ld_coh16(pIhi + fo);
                        bf16x8 vIlo = ld_coh16(pIlo + fo);
                        #pragma unroll
                        for (int g = 0; g < 3; ++g) {
                            acc_i[m2][g] = __builtin_amdgcn_mfma_f32_16x16x32_bf16(wiR[kk][g], vIlo, acc_i[m2][g], 0, 0, 0);
                            acc_i[m2][g] = __builtin_amdgcn_mfma_f32_16x16x32_bf16(wiR[kk][g], vIhi, acc_i[m2][g], 0, 0, 0);
                        }
                    }
                    #pragma unroll
                    for (int g = 0; g < 3; ++g) {
                        acc_h[m2][g] = __builtin_amdgcn_mfma_f32_16x16x32_bf16(whR[kk][g], vHlo, acc_h[m2][g], 0, 0, 0);
                        acc_h[m2][g] = __builtin_amdgcn_mfma_f32_16x16x32_bf16(whR[kk][g], vHhi, acc_h[m2][g], 0, 0, 0);
                    }
                }
            }

            if (kq != 0) {
                float* p = &ldsRed[kq - 1][lane][0];
                #pragma unroll
                for (int m2 = 0; m2 < 2; ++m2)
                    #pragma unroll
                    for (int g = 0; g < 3; ++g) {
                        *(f32x4*)(p + m2 * 24 + g * 4)      = acc_i[m2][g];
                        *(f32x4*)(p + m2 * 24 + 12 + g * 4) = acc_h[m2][g];
                    }
            }
            __syncthreads();                   // (A)
            if (kq == 0) {
                #pragma unroll
                for (int q = 0; q < 3; ++q) {
                    const float* p = &ldsRed[q][lane][0];
                    #pragma unroll
                    for (int m2 = 0; m2 < 2; ++m2)
                        #pragma unroll
                        for (int g = 0; g < 3; ++g) {
                            acc_i[m2][g] += *(const f32x4*)(p + m2 * 24 + g * 4);
                            acc_h[m2][g] += *(const f32x4*)(p + m2 * 24 + 12 + g * 4);
                        }
                }
                unsigned short* dsthi = layer ? h1hi[wp] : h0hi[wp];
                unsigned short* dstlo = layer ? h1lo[wp] : h0lo[wp];
                const int klocal0 = ((nt & 1) << 4) + (l4 << 2);
                const int lanep = l15 | ((klocal0 >> 3) << 4);
                const int chunk = nt >> 1;
                #pragma unroll
                for (int m2 = 0; m2 < 2; ++m2) {
                    u16x4 shi, slo; f32x4 hv;
                    #pragma unroll
                    for (int r = 0; r < 4; ++r) {
                        float vr = acc_i[m2][0][r] + acc_h[m2][0][r] + br[r];
                        float vz = acc_i[m2][1][r] + acc_h[m2][1][r] + bz[r];
                        float rg = sigm(vr);
                        float zg = sigm(vz);
                        float ng = tanh_(acc_i[m2][2][r] + bni[r] + rg * (acc_h[m2][2][r] + bnh[r]));
                        float h  = (1.0f - zg) * ng + zg * hold[m2][r];
                        hold[m2][r] = h;
                        hv[r] = h;
                        unsigned short hb = f2bf(h);
                        shi[r] = hb;
                        slo[r] = f2bf(h - bf2f(hb));
                    }
                    const int eo = ((((tile0 + m2) * 16 + chunk) * 64) + lanep) * 8 + (klocal0 & 7);
                    st_llc8(dsthi + eo, __builtin_bit_cast(unsigned long long, shi));
                    st_llc8(dstlo + eo, __builtin_bit_cast(unsigned long long, slo));
                    if (layer && s == TS) {
                        const int m = (tile0 + m2) * 16 + l15;
                        const int kg0 = nt * 16 + (l4 << 2);
                        st_llc16(h1f + (size_t)m * HID + kg0, hv);
                    }
                }
            }
        }

        // ---- arrive (release: stores ACKed at LLC before leaf add) ----
        if (tid == 0) {
            asm volatile("s_waitcnt vmcnt(0)" ::: "memory");
            unsigned old = __hip_atomic_fetch_add(leaf, 1u, __ATOMIC_RELAXED, __HIP_MEMORY_SCOPE_AGENT);
            if (old == (unsigned)(s * 8 + 7))
                __hip_atomic_fetch_add(master, 1u, __ATOMIC_RELAXED, __HIP_MEMORY_SCOPE_AGENT);
        }

        // ---- barrier window: layer-0 computes next step's x-GEMM ----
        if (layer == 0 && s + 1 < TS) {
            #pragma unroll
            for (int m2 = 0; m2 < 2; ++m2)
                #pragma unroll
                for (int g = 0; g < 3; ++g)
                    acc_i[m2][g] = (f32x4){0.f,0.f,0.f,0.f};
            l0_input_mfma(s + 1);
        }

        // ---- spin ----
        if (tid == 0) {
            const unsigned tgt = (unsigned)((s + 1) * 8);
            while (__hip_atomic_load(master, __ATOMIC_RELAXED, __HIP_MEMORY_SCOPE_AGENT) < tgt)
                __builtin_amdgcn_s_sleep(1);
        }
        __syncthreads();                   // (B)
    }

    // ---- global fin barrier, then FC epilogue (layer-0 wgs) ----
    if (tid == 0) {
        asm volatile("s_waitcnt vmcnt(0)" ::: "memory");
        __hip_atomic_fetch_add(fin, 1u, __ATOMIC_RELAXED, __HIP_MEMORY_SCOPE_AGENT);
    }
    if (wgid < 64) {
        float* fw = (float*)ldsRed;               // 8 rows x 516 floats
        const float* src = fcw + (size_t)wgid * 8 * HID;
        for (int i = tid; i < (8 * HID) / 4; i += WGT) {
            f32x4 v = *(const f32x4*)(src + i * 4);
            int row = (i * 4) >> 9;
            int kk  = (i * 4) & 511;
            *(f32x4*)(fw + row * 516 + kk) = v;
        }
        if (tid == 0) {
            while (__hip_atomic_load(fin, __ATOMIC_RELAXED, __HIP_MEMORY_SCOPE_AGENT) < (unsigned)NWG)
                __builtin_amdgcn_s_sleep(1);
        }
        __syncthreads();
        const int col = wgid * 8 + (tid & 7);
        const int m0  = tid >> 3;
        float a0 = fcb[col], a1 = a0, a2 = a0, a3 = a0;
        const float* fwr = fw + (tid & 7) * 516;
        for (int k = 0; k < HID; k += 4) {
            f32x4 wv  = *(const f32x4*)(fwr + k);
            f32x4 h0v = ld_coh16f(h1f + (size_t)(m0)      * HID + k);
            f32x4 h1v = ld_coh16f(h1f + (size_t)(m0 + 32) * HID + k);
            f32x4 h2v = ld_coh16f(h1f + (size_t)(m0 + 64) * HID + k);
            f32x4 h3v = ld_coh16f(h1f + (size_t)(m0 + 96) * HID + k);
            a0 += h0v[0]*wv[0] + h0v[1]*wv[1] + h0v[2]*wv[2] + h0v[3]*wv[3];
            a1 += h1v[0]*wv[0] + h1v[1]*wv[1] + h1v[2]*wv[2] + h1v[3]*wv[3];
            a2 += h2v[0]*wv[0] + h2v[1]*wv[1] + h2v[2]*wv[2] + h2v[3]*wv[3];
            a3 += h3v[0]*wv[0] + h3v[1]*wv[1] + h3v[2]*wv[2] + h3v[3]*wv[3];
        }
        out[(size_t)(m0)      * HID + col] = a0;
        out[(size_t)(m0 + 32) * HID + col] = a1;
        out[(size_t)(m0 + 64) * HID + col] = a2;
        out[(size_t)(m0 + 96) * HID + col] = a3;
    }
}

extern "C" void kernel_launch(void* const* d_in, const int* in_sizes, int n_in,
                              void* d_out, int out_size, void* d_ws, size_t ws_size,
                              hipStream_t stream) {
    (void)in_sizes; (void)n_in; (void)out_size; (void)ws_size;
    hipMemsetAsync(d_ws, 0, WS_ZERO, stream);
    gru_persistent<<<dim3(NWG), dim3(WGT), 0, stream>>>(
        (const float*)d_in[0],
        (const float*)d_in[1], (const float*)d_in[2],
        (const float*)d_in[3], (const float*)d_in[4],
        (const float*)d_in[5], (const float*)d_in[6],
        (const float*)d_in[7], (const float*)d_in[8],
        (const float*)d_in[9], (const float*)d_in[10],
        (float*)d_out, (unsigned char*)d_ws);
}

// Round 4
// 8967.171 us; speedup vs baseline: 2.6464x; 1.0300x over previous
//
#include <hip/hip_runtime.h>

// ---------------------------------------------------------------------------
// Persistent 2-layer GRU for MI355X (gfx950).  B=128, T=1024, D=H=512.
// 256 wgs x 256 thr, 1 wg/CU. wg = (layer, mt, nt): 32 batch rows x 16 hid cols.
// Waves k-split K=512 into 4x128; weights in REGISTERS (24 bf16x8 frags/matrix).
// ZERO cache-maintenance ops and ZERO atomic-RMW barriers in the loop:
//   h handoff = write-through (sc0 sc1) stores + agent-scope relaxed atomic
//   loads (LLC-direct).  Barrier = per-wg monotonic seq word (plain coherent
//   store) + vectorized coherent poll of the 64-entry group array (no RMW
//   hot-spot, no master line camping).
// Layer-0's x-GEMM for step s+1 runs inside the barrier window, using a
// truncation-based hi/lo bf16 split (integer pair-packing, ~4.5 inst/elem).
// ---------------------------------------------------------------------------

#define TS   1024
#define HID  512
#define NWG  256
#define WGT  256

typedef __attribute__((ext_vector_type(8))) short bf16x8;
typedef __attribute__((ext_vector_type(4))) unsigned short u16x4;
typedef __attribute__((ext_vector_type(4))) float f32x4;

#define WS_SEQ      0          // 4 mt-groups x 64 u32, 256B apart
#define WS_FIN      2048
#define WS_HBUF     8192
#define HBUF_ELEMS  65536                             // 128*512 bf16 per buffer
#define WS_H1F      (WS_HBUF + 8 * HBUF_ELEMS * 2)    // fp32 [128][512]
#define WS_ZERO     (WS_HBUF + 8 * HBUF_ELEMS * 2)

__device__ __forceinline__ unsigned short f2bf(float f) {
    unsigned u = __float_as_uint(f);
    u += 0x7FFFu + ((u >> 16) & 1u);
    return (unsigned short)(u >> 16);
}
__device__ __forceinline__ float bf2f(unsigned short s) {
    return __uint_as_float(((unsigned)s) << 16);
}
__device__ __forceinline__ float sigm(float v) { return 1.0f / (1.0f + __expf(-v)); }
__device__ __forceinline__ float tanh_(float v) { return 1.0f - 2.0f / (1.0f + __expf(2.0f * v)); }

// write-through to LLC (device coherence point)
__device__ __forceinline__ void st_llc8(void* p, unsigned long long v) {
    asm volatile("global_store_dwordx2 %0, %1, off sc0 sc1" :: "v"(p), "v"(v) : "memory");
}
__device__ __forceinline__ void st_llc16(void* p, f32x4 v) {
    asm volatile("global_store_dwordx4 %0, %1, off sc0 sc1" :: "v"(p), "v"(v) : "memory");
}
// coherent 16B load (2x agent-scope relaxed u64 atomic loads)
__device__ __forceinline__ bf16x8 ld_coh16(const unsigned short* p) {
    const unsigned long long* q = (const unsigned long long*)p;
    union { unsigned long long u[2]; bf16x8 v; } r;
    r.u[0] = __hip_atomic_load(q,     __ATOMIC_RELAXED, __HIP_MEMORY_SCOPE_AGENT);
    r.u[1] = __hip_atomic_load(q + 1, __ATOMIC_RELAXED, __HIP_MEMORY_SCOPE_AGENT);
    return r.v;
}
__device__ __forceinline__ f32x4 ld_coh16f(const float* p) {
    const unsigned long long* q = (const unsigned long long*)p;
    union { unsigned long long u[2]; f32x4 v; } r;
    r.u[0] = __hip_atomic_load(q,     __ATOMIC_RELAXED, __HIP_MEMORY_SCOPE_AGENT);
    r.u[1] = __hip_atomic_load(q + 1, __ATOMIC_RELAXED, __HIP_MEMORY_SCOPE_AGENT);
    return r.v;
}

__global__ void __launch_bounds__(WGT, 1)
gru_persistent(const float* __restrict__ x,
               const float* __restrict__ wi0, const float* __restrict__ wh0,
               const float* __restrict__ bi0, const float* __restrict__ bh0,
               const float* __restrict__ wi1, const float* __restrict__ wh1,
               const float* __restrict__ bi1, const float* __restrict__ bh1,
               const float* __restrict__ fcw, const float* __restrict__ fcb,
               float* __restrict__ out, unsigned char* __restrict__ ws)
{
    __shared__ float ldsRed[3][64][52];        // 39936 B k-split partials

    const int tid   = threadIdx.x;
    const int lane  = tid & 63;
    const int kq    = tid >> 6;                // wave id = k-quarter
    const int wgid  = blockIdx.x;
    const int layer = wgid >> 7;
    const int wid   = wgid & 127;
    const int mt    = wid & 3;                 // 32-row m-tile (barrier group)
    const int nt    = wid >> 2;                // 16-col hidden tile
    const int l15   = lane & 15;
    const int l4    = lane >> 4;
    const int tile0 = mt * 2;
    const int gidx  = layer * 32 + nt;         // 0..63 within mt-group

    unsigned* seqA = (unsigned*)(ws + WS_SEQ + (size_t)mt * 256);
    unsigned* fin  = (unsigned*)(ws + WS_FIN);
    unsigned short* hbm = (unsigned short*)(ws + WS_HBUF);
    float* h1f = (float*)(ws + WS_H1F);

    unsigned short* h0hi[2] = { hbm + 0 * HBUF_ELEMS, hbm + 1 * HBUF_ELEMS };
    unsigned short* h0lo[2] = { hbm + 2 * HBUF_ELEMS, hbm + 3 * HBUF_ELEMS };
    unsigned short* h1hi[2] = { hbm + 4 * HBUF_ELEMS, hbm + 5 * HBUF_ELEMS };
    unsigned short* h1lo[2] = { hbm + 6 * HBUF_ELEMS, hbm + 7 * HBUF_ELEMS };

    // ---- stage weight fragments into REGISTERS (fp32 -> bf16) ----
    bf16x8 wiR[4][3], whR[4][3];
    {
        const float* Wi = layer ? wi1 : wi0;
        const float* Wh = layer ? wh1 : wh0;
        #pragma unroll
        for (int kk = 0; kk < 4; ++kk) {
            const int kc = (kq << 2) + kk;
            #pragma unroll
            for (int g = 0; g < 3; ++g) {
                const int jg = g * HID + nt * 16 + l15;
                const float* pi = Wi + (size_t)jg * HID + kc * 32 + (l4 << 3);
                const float* ph = Wh + (size_t)jg * HID + kc * 32 + (l4 << 3);
                #pragma unroll
                for (int e = 0; e < 8; ++e) {
                    wiR[kk][g][e] = (short)f2bf(pi[e]);
                    whR[kk][g][e] = (short)f2bf(ph[e]);
                }
            }
        }
    }

    // ---- per-thread biases (wave 0 only) ----
    float br[4] = {0,0,0,0}, bz[4] = {0,0,0,0}, bni[4] = {0,0,0,0}, bnh[4] = {0,0,0,0};
    if (kq == 0) {
        const float* Bi = layer ? bi1 : bi0;
        const float* Bh = layer ? bh1 : bh0;
        int c0 = nt * 16 + (l4 << 2);
        #pragma unroll
        for (int r = 0; r < 4; ++r) {
            int j = c0 + r;
            br[r]  = Bi[j] + Bh[j];
            bz[r]  = Bi[HID + j] + Bh[HID + j];
            bni[r] = Bi[2 * HID + j];
            bnh[r] = Bh[2 * HID + j];
        }
    }

    float hold[2][4] = {{0,0,0,0},{0,0,0,0}};
    f32x4 acc_i[2][3], acc_h[2][3];
    #pragma unroll
    for (int m2 = 0; m2 < 2; ++m2)
        #pragma unroll
        for (int g = 0; g < 3; ++g) {
            acc_i[m2][g] = (f32x4){0.f,0.f,0.f,0.f};
            acc_h[m2][g] = (f32x4){0.f,0.f,0.f,0.f};
        }

    // truncation-based hi/lo split of two f32 -> packed u32 pair
    auto splitPack = [](float a, float b, unsigned& hiw, unsigned& low) {
        unsigned ba = __float_as_uint(a), bb = __float_as_uint(b);
        unsigned ha = ba & 0xFFFF0000u,   hb = bb & 0xFFFF0000u;
        float la = a - __uint_as_float(ha);
        float lb = b - __uint_as_float(hb);
        hiw = (ba >> 16) | hb;
        low = (__float_as_uint(la) >> 16) | (__float_as_uint(lb) & 0xFFFF0000u);
    };

    // layer-0 x-side GEMM for step sn (h-independent, runs in barrier window)
    auto l0_input_mfma = [&](int sn) {
        #pragma unroll
        for (int kk = 0; kk < 4; ++kk) {
            const int kc = (kq << 2) + kk;
            #pragma unroll
            for (int m2 = 0; m2 < 2; ++m2) {
                const int m = (tile0 + m2) * 16 + l15;
                const int k = kc * 32 + (l4 << 3);
                const float* xp = x + ((size_t)m * TS + sn) * HID + k;
                f32x4 xa = *(const f32x4*)xp;
                f32x4 xb = *(const f32x4*)(xp + 4);
                union { unsigned u[4]; bf16x8 v; } hi, lo;
                splitPack(xa[0], xa[1], hi.u[0], lo.u[0]);
                splitPack(xa[2], xa[3], hi.u[1], lo.u[1]);
                splitPack(xb[0], xb[1], hi.u[2], lo.u[2]);
                splitPack(xb[2], xb[3], hi.u[3], lo.u[3]);
                #pragma unroll
                for (int g = 0; g < 3; ++g) {
                    acc_i[m2][g] = __builtin_amdgcn_mfma_f32_16x16x32_bf16(wiR[kk][g], lo.v, acc_i[m2][g], 0, 0, 0);
                    acc_i[m2][g] = __builtin_amdgcn_mfma_f32_16x16x32_bf16(wiR[kk][g], hi.v, acc_i[m2][g], 0, 0, 0);
                }
            }
        }
    };

    __syncthreads();
    if (layer == 0) l0_input_mfma(0);          // prologue: acc_i for step 0

    for (int s = 0; s <= TS; ++s) {
        const int wp = s & 1, rp = wp ^ 1;
        const bool active = layer ? (s >= 1) : (s < TS);
        if (active) {
            #pragma unroll
            for (int m2 = 0; m2 < 2; ++m2)
                #pragma unroll
                for (int g = 0; g < 3; ++g) {
                    acc_h[m2][g] = (f32x4){0.f,0.f,0.f,0.f};
                    if (layer) acc_i[m2][g] = (f32x4){0.f,0.f,0.f,0.f};
                }

            const unsigned short* pIhi = h0hi[rp];
            const unsigned short* pIlo = h0lo[rp];
            const unsigned short* pHhi = layer ? h1hi[rp] : h0hi[rp];
            const unsigned short* pHlo = layer ? h1lo[rp] : h0lo[rp];

            #pragma unroll
            for (int kk = 0; kk < 4; ++kk) {
                const int kc = (kq << 2) + kk;
                #pragma unroll
                for (int m2 = 0; m2 < 2; ++m2) {
                    const int fo = ((((tile0 + m2) * 16 + kc) * 64) + lane) * 8;
                    bf16x8 vHhi = ld_coh16(pHhi + fo);
                    bf16x8 vHlo = ld_coh16(pHlo + fo);
                    if (layer) {
                        bf16x8 vIhi = ld_coh16(pIhi + fo);
                        bf16x8 vIlo = ld_coh16(pIlo + fo);
                        #pragma unroll
                        for (int g = 0; g < 3; ++g) {
                            acc_i[m2][g] = __builtin_amdgcn_mfma_f32_16x16x32_bf16(wiR[kk][g], vIlo, acc_i[m2][g], 0, 0, 0);
                            acc_i[m2][g] = __builtin_amdgcn_mfma_f32_16x16x32_bf16(wiR[kk][g], vIhi, acc_i[m2][g], 0, 0, 0);
                        }
                    }
                    #pragma unroll
                    for (int g = 0; g < 3; ++g) {
                        acc_h[m2][g] = __builtin_amdgcn_mfma_f32_16x16x32_bf16(whR[kk][g], vHlo, acc_h[m2][g], 0, 0, 0);
                        acc_h[m2][g] = __builtin_amdgcn_mfma_f32_16x16x32_bf16(whR[kk][g], vHhi, acc_h[m2][g], 0, 0, 0);
                    }
                }
            }

            if (kq != 0) {
                float* p = &ldsRed[kq - 1][lane][0];
                #pragma unroll
                for (int m2 = 0; m2 < 2; ++m2)
                    #pragma unroll
                    for (int g = 0; g < 3; ++g) {
                        *(f32x4*)(p + m2 * 24 + g * 4)      = acc_i[m2][g];
                        *(f32x4*)(p + m2 * 24 + 12 + g * 4) = acc_h[m2][g];
                    }
            }
            __syncthreads();                   // (A)
            if (kq == 0) {
                #pragma unroll
                for (int q = 0; q < 3; ++q) {
                    const float* p = &ldsRed[q][lane][0];
                    #pragma unroll
                    for (int m2 = 0; m2 < 2; ++m2)
                        #pragma unroll
                        for (int g = 0; g < 3; ++g) {
                            acc_i[m2][g] += *(const f32x4*)(p + m2 * 24 + g * 4);
                            acc_h[m2][g] += *(const f32x4*)(p + m2 * 24 + 12 + g * 4);
                        }
                }
                unsigned short* dsthi = layer ? h1hi[wp] : h0hi[wp];
                unsigned short* dstlo = layer ? h1lo[wp] : h0lo[wp];
                const int klocal0 = ((nt & 1) << 4) + (l4 << 2);
                const int lanep = l15 | ((klocal0 >> 3) << 4);
                const int chunk = nt >> 1;
                #pragma unroll
                for (int m2 = 0; m2 < 2; ++m2) {
                    u16x4 shi, slo; f32x4 hv;
                    #pragma unroll
                    for (int r = 0; r < 4; ++r) {
                        float vr = acc_i[m2][0][r] + acc_h[m2][0][r] + br[r];
                        float vz = acc_i[m2][1][r] + acc_h[m2][1][r] + bz[r];
                        float rg = sigm(vr);
                        float zg = sigm(vz);
                        float ng = tanh_(acc_i[m2][2][r] + bni[r] + rg * (acc_h[m2][2][r] + bnh[r]));
                        float h  = (1.0f - zg) * ng + zg * hold[m2][r];
                        hold[m2][r] = h;
                        hv[r] = h;
                        unsigned short hb = f2bf(h);
                        shi[r] = hb;
                        slo[r] = f2bf(h - bf2f(hb));
                    }
                    const int eo = ((((tile0 + m2) * 16 + chunk) * 64) + lanep) * 8 + (klocal0 & 7);
                    st_llc8(dsthi + eo, __builtin_bit_cast(unsigned long long, shi));
                    st_llc8(dstlo + eo, __builtin_bit_cast(unsigned long long, slo));
                    if (layer && s == TS) {
                        const int m = (tile0 + m2) * 16 + l15;
                        const int kg0 = nt * 16 + (l4 << 2);
                        st_llc16(h1f + (size_t)m * HID + kg0, hv);
                    }
                }
            }
        }

        // ---- arrive: drain stores, publish seq (plain coherent store) ----
        if (tid == 0) {
            asm volatile("s_waitcnt vmcnt(0)" ::: "memory");
            __hip_atomic_store(&seqA[gidx], (unsigned)(s + 1),
                               __ATOMIC_RELAXED, __HIP_MEMORY_SCOPE_AGENT);
        }

        // ---- barrier window: layer-0 computes next step's x-GEMM ----
        if (layer == 0 && s + 1 < TS) {
            #pragma unroll
            for (int m2 = 0; m2 < 2; ++m2)
                #pragma unroll
                for (int g = 0; g < 3; ++g)
                    acc_i[m2][g] = (f32x4){0.f,0.f,0.f,0.f};
            l0_input_mfma(s + 1);
        }

        // ---- poll: all 64 group seqs >= s+1 (vector coherent loads) ----
        if (kq == 0) {
            const unsigned long long* sp =
                (const unsigned long long*)(seqA + ((lane & 15) << 2));
            const unsigned tgt = (unsigned)(s + 1);
            for (;;) {
                unsigned long long a = __hip_atomic_load(sp,     __ATOMIC_RELAXED, __HIP_MEMORY_SCOPE_AGENT);
                unsigned long long b = __hip_atomic_load(sp + 1, __ATOMIC_RELAXED, __HIP_MEMORY_SCOPE_AGENT);
                bool ok = ((unsigned)a >= tgt) && ((unsigned)(a >> 32) >= tgt) &&
                          ((unsigned)b >= tgt) && ((unsigned)(b >> 32) >= tgt);
                if (__all(ok)) break;
                __builtin_amdgcn_s_sleep(1);
            }
        }
        __syncthreads();                   // (B)
    }

    // ---- global fin barrier (one-shot), then FC epilogue ----
    if (tid == 0) {
        asm volatile("s_waitcnt vmcnt(0)" ::: "memory");
        __hip_atomic_fetch_add(fin, 1u, __ATOMIC_RELAXED, __HIP_MEMORY_SCOPE_AGENT);
    }
    if (wgid < 64) {
        float* fw = (float*)ldsRed;               // 8 rows x 516 floats
        const float* src = fcw + (size_t)wgid * 8 * HID;
        for (int i = tid; i < (8 * HID) / 4; i += WGT) {
            f32x4 v = *(const f32x4*)(src + i * 4);
            int row = (i * 4) >> 9;
            int kk  = (i * 4) & 511;
            *(f32x4*)(fw + row * 516 + kk) = v;
        }
        if (tid == 0) {
            while (__hip_atomic_load(fin, __ATOMIC_RELAXED, __HIP_MEMORY_SCOPE_AGENT) < (unsigned)NWG)
                __builtin_amdgcn_s_sleep(1);
        }
        __syncthreads();
        const int col = wgid * 8 + (tid & 7);
        const int m0  = tid >> 3;
        float a0 = fcb[col], a1 = a0, a2 = a0, a3 = a0;
        const float* fwr = fw + (tid & 7) * 516;
        for (int k = 0; k < HID; k += 4) {
            f32x4 wv  = *(const f32x4*)(fwr + k);
            f32x4 h0v = ld_coh16f(h1f + (size_t)(m0)      * HID + k);
            f32x4 h1v = ld_coh16f(h1f + (size_t)(m0 + 32) * HID + k);
            f32x4 h2v = ld_coh16f(h1f + (size_t)(m0 + 64) * HID + k);
            f32x4 h3v = ld_coh16f(h1f + (size_t)(m0 + 96) * HID + k);
            a0 += h0v[0]*wv[0] + h0v[1]*wv[1] + h0v[2]*wv[2] + h0v[3]*wv[3];
            a1 += h1v[0]*wv[0] + h1v[1]*wv[1] + h1v[2]*wv[2] + h1v[3]*wv[3];
            a2 += h2v[0]*wv[0] + h2v[1]*wv[1] + h2v[2]*wv[2] + h2v[3]*wv[3];
            a3 += h3v[0]*wv[0] + h3v[1]*wv[1] + h3v[2]*wv[2] + h3v[3]*wv[3];
        }
        out[(size_t)(m0)      * HID + col] = a0;
        out[(size_t)(m0 + 32) * HID + col] = a1;
        out[(size_t)(m0 + 64) * HID + col] = a2;
        out[(size_t)(m0 + 96) * HID + col] = a3;
    }
}

extern "C" void kernel_launch(void* const* d_in, const int* in_sizes, int n_in,
                              void* d_out, int out_size, void* d_ws, size_t ws_size,
                              hipStream_t stream) {
    (void)in_sizes; (void)n_in; (void)out_size; (void)ws_size;
    hipMemsetAsync(d_ws, 0, WS_ZERO, stream);
    gru_persistent<<<dim3(NWG), dim3(WGT), 0, stream>>>(
        (const float*)d_in[0],
        (const float*)d_in[1], (const float*)d_in[2],
        (const float*)d_in[3], (const float*)d_in[4],
        (const float*)d_in[5], (const float*)d_in[6],
        (const float*)d_in[7], (const float*)d_in[8],
        (const float*)d_in[9], (const float*)d_in[10],
        (float*)d_out, (unsigned char*)d_ws);
}

// Round 5
// 8780.817 us; speedup vs baseline: 2.7026x; 1.0212x over previous
//
#include <hip/hip_runtime.h>

// ---------------------------------------------------------------------------
// Persistent 2-layer GRU for MI355X (gfx950).  B=128, T=1024, D=H=512.
// 256 wgs x 256 thr, 1 wg/CU. wg = (layer, mtile, ntile): 16 batch rows x 32
// hidden cols (96 gate rows). TALL-NARROW tiles halve the per-wg coherent h
// operand traffic (reads scale with m-rows). Waves k-split K=512 into 4x128;
// weights live in REGISTERS (48 bf16x8 frags/wave = 192 VGPR).
// h handoff: write-through (sc0 sc1) stores + BATCHED asm coherent loads
// (all issued, one vmcnt(0)+sched_barrier, then MFMAs) -> single latency
// exposure per interval. Barrier: 8 independent per-mtile groups of 32 wgs,
// per-wg monotonic seq words + vector poll. L0 stashes x(s+1) in registers
// during the batch; window x-GEMM is pure VALU+MFMA.
// ---------------------------------------------------------------------------

#define TS   1024
#define HID  512
#define NWG  256
#define WGT  256

typedef __attribute__((ext_vector_type(8))) short bf16x8;
typedef __attribute__((ext_vector_type(4))) unsigned short u16x4;
typedef __attribute__((ext_vector_type(4))) float f32x4;

#define WS_FIN      2048
#define WS_HBUF     8192
#define HBUF_ELEMS  65536                             // 128*512 bf16 per buffer
#define WS_H1F      (WS_HBUF + 8 * HBUF_ELEMS * 2)    // fp32 [128][512]
#define WS_ZERO     (WS_HBUF + 8 * HBUF_ELEMS * 2)

__device__ __forceinline__ unsigned short f2bf(float f) {
    unsigned u = __float_as_uint(f);
    u += 0x7FFFu + ((u >> 16) & 1u);
    return (unsigned short)(u >> 16);
}
__device__ __forceinline__ float bf2f(unsigned short s) {
    return __uint_as_float(((unsigned)s) << 16);
}
__device__ __forceinline__ float sigm(float v) { return 1.0f / (1.0f + __expf(-v)); }
__device__ __forceinline__ float tanh_(float v) { return 1.0f - 2.0f / (1.0f + __expf(2.0f * v)); }

// write-through to LLC (device coherence point)
__device__ __forceinline__ void st_llc8(void* p, unsigned long long v) {
    asm volatile("global_store_dwordx2 %0, %1, off sc0 sc1" :: "v"(p), "v"(v) : "memory");
}
__device__ __forceinline__ void st_llc16(void* p, f32x4 v) {
    asm volatile("global_store_dwordx4 %0, %1, off sc0 sc1" :: "v"(p), "v"(v) : "memory");
}
// issue-only loads; caller must wait_vm0() before consuming results
__device__ __forceinline__ void ld_coh16_issue(bf16x8& d, const unsigned short* p) {
    asm volatile("global_load_dwordx4 %0, %1, off sc0 sc1" : "=v"(d) : "v"(p));
}
__device__ __forceinline__ void ld16_issue(f32x4& d, const float* p) {
    asm volatile("global_load_dwordx4 %0, %1, off" : "=v"(d) : "v"(p));
}
__device__ __forceinline__ void wait_vm0() {
    asm volatile("s_waitcnt vmcnt(0)" ::: "memory");
    __builtin_amdgcn_sched_barrier(0);
}
// coherent 16B fp32 load (FC epilogue only)
__device__ __forceinline__ f32x4 ld_coh16f(const float* p) {
    const unsigned long long* q = (const unsigned long long*)p;
    union { unsigned long long u[2]; f32x4 v; } r;
    r.u[0] = __hip_atomic_load(q,     __ATOMIC_RELAXED, __HIP_MEMORY_SCOPE_AGENT);
    r.u[1] = __hip_atomic_load(q + 1, __ATOMIC_RELAXED, __HIP_MEMORY_SCOPE_AGENT);
    return r.v;
}

__global__ void __launch_bounds__(WGT, 1)
gru_persistent(const float* __restrict__ x,
               const float* __restrict__ wi0, const float* __restrict__ wh0,
               const float* __restrict__ bi0, const float* __restrict__ bh0,
               const float* __restrict__ wi1, const float* __restrict__ wh1,
               const float* __restrict__ bi1, const float* __restrict__ bh1,
               const float* __restrict__ fcw, const float* __restrict__ fcb,
               float* __restrict__ out, unsigned char* __restrict__ ws)
{
    __shared__ float ldsRed[3][64][49];        // 37632 B k-split partials

    const int tid   = threadIdx.x;
    const int lane  = tid & 63;
    const int kq    = tid >> 6;                // wave id = k-quarter
    const int wgid  = blockIdx.x;
    const int layer = wgid >> 7;
    const int wid   = wgid & 127;
    const int mtile = wid & 7;                 // 16-row m-tile (barrier group)
    const int ntile = wid >> 3;                // 32-col hidden tile
    const int l15   = lane & 15;
    const int l4    = lane >> 4;
    const int gidx  = layer * 16 + ntile;      // 0..31 within mtile-group

    unsigned* seqA = (unsigned*)(ws + (size_t)mtile * 256);
    unsigned* fin  = (unsigned*)(ws + WS_FIN);
    unsigned short* hbm = (unsigned short*)(ws + WS_HBUF);
    float* h1f = (float*)(ws + WS_H1F);

    unsigned short* h0hi[2] = { hbm + 0 * HBUF_ELEMS, hbm + 1 * HBUF_ELEMS };
    unsigned short* h0lo[2] = { hbm + 2 * HBUF_ELEMS, hbm + 3 * HBUF_ELEMS };
    unsigned short* h1hi[2] = { hbm + 4 * HBUF_ELEMS, hbm + 5 * HBUF_ELEMS };
    unsigned short* h1lo[2] = { hbm + 6 * HBUF_ELEMS, hbm + 7 * HBUF_ELEMS };

    // ---- stage weight fragments into REGISTERS (fp32 -> bf16) ----
    // frag f = g*2 + n2: gate rows g*512 + ntile*32 + n2*16 + l15
    bf16x8 wiR[4][6], whR[4][6];
    {
        const float* Wi = layer ? wi1 : wi0;
        const float* Wh = layer ? wh1 : wh0;
        #pragma unroll
        for (int kk = 0; kk < 4; ++kk) {
            const int kc = (kq << 2) + kk;
            #pragma unroll
            for (int f = 0; f < 6; ++f) {
                const int g = f >> 1, n2 = f & 1;
                const int jg = g * HID + ntile * 32 + n2 * 16 + l15;
                const float* pi = Wi + (size_t)jg * HID + kc * 32 + (l4 << 3);
                const float* ph = Wh + (size_t)jg * HID + kc * 32 + (l4 << 3);
                #pragma unroll
                for (int e = 0; e < 8; ++e) {
                    wiR[kk][f][e] = (short)f2bf(pi[e]);
                    whR[kk][f][e] = (short)f2bf(ph[e]);
                }
            }
        }
    }

    // ---- per-thread biases (wave 0 only): 8 outputs (n2, r) per lane ----
    float br[2][4], bz[2][4], bni[2][4], bnh[2][4];
    if (kq == 0) {
        const float* Bi = layer ? bi1 : bi0;
        const float* Bh = layer ? bh1 : bh0;
        #pragma unroll
        for (int n2 = 0; n2 < 2; ++n2)
            #pragma unroll
            for (int r = 0; r < 4; ++r) {
                int j = ntile * 32 + n2 * 16 + (l4 << 2) + r;
                br[n2][r]  = Bi[j] + Bh[j];
                bz[n2][r]  = Bi[HID + j] + Bh[HID + j];
                bni[n2][r] = Bi[2 * HID + j];
                bnh[n2][r] = Bh[2 * HID + j];
            }
    } else {
        #pragma unroll
        for (int n2 = 0; n2 < 2; ++n2)
            #pragma unroll
            for (int r = 0; r < 4; ++r)
                br[n2][r] = bz[n2][r] = bni[n2][r] = bnh[n2][r] = 0.f;
    }

    float hold[2][4] = {{0,0,0,0},{0,0,0,0}};
    f32x4 acc_i[6], acc_h[6];
    #pragma unroll
    for (int f = 0; f < 6; ++f) {
        acc_i[f] = (f32x4){0.f,0.f,0.f,0.f};
        acc_h[f] = (f32x4){0.f,0.f,0.f,0.f};
    }

    f32x4 xs[4][2];                            // x stash for step s+1 (L0)

    auto splitPack = [](float a, float b, unsigned& hiw, unsigned& low) {
        unsigned ba = __float_as_uint(a), bb = __float_as_uint(b);
        unsigned ha = ba & 0xFFFF0000u,   hb = bb & 0xFFFF0000u;
        float la = a - __uint_as_float(ha);
        float lb = b - __uint_as_float(hb);
        hiw = (ba >> 16) | hb;
        low = (__float_as_uint(la) >> 16) | (__float_as_uint(lb) & 0xFFFF0000u);
    };

    // window x-GEMM from stashed registers: zero acc_i, split, 48 MFMAs
    auto do_window = [&]() {
        #pragma unroll
        for (int f = 0; f < 6; ++f) acc_i[f] = (f32x4){0.f,0.f,0.f,0.f};
        #pragma unroll
        for (int kk = 0; kk < 4; ++kk) {
            union { unsigned u[4]; bf16x8 v; } hi, lo;
            splitPack(xs[kk][0][0], xs[kk][0][1], hi.u[0], lo.u[0]);
            splitPack(xs[kk][0][2], xs[kk][0][3], hi.u[1], lo.u[1]);
            splitPack(xs[kk][1][0], xs[kk][1][1], hi.u[2], lo.u[2]);
            splitPack(xs[kk][1][2], xs[kk][1][3], hi.u[3], lo.u[3]);
            #pragma unroll
            for (int f = 0; f < 6; ++f) {
                acc_i[f] = __builtin_amdgcn_mfma_f32_16x16x32_bf16(wiR[kk][f], lo.v, acc_i[f], 0, 0, 0);
                acc_i[f] = __builtin_amdgcn_mfma_f32_16x16x32_bf16(wiR[kk][f], hi.v, acc_i[f], 0, 0, 0);
            }
        }
    };

    // ---- prologue: x-GEMM for step 0 (L0) ----
    if (layer == 0) {
        #pragma unroll
        for (int kk = 0; kk < 4; ++kk) {
            const int m = mtile * 16 + l15;
            const int k = ((kq << 2) + kk) * 32 + (l4 << 3);
            const float* xp = x + ((size_t)m * TS + 0) * HID + k;
            ld16_issue(xs[kk][0], xp);
            ld16_issue(xs[kk][1], xp + 4);
        }
        wait_vm0();
        do_window();
    }

    for (int s = 0; s <= TS; ++s) {
        const int wp = s & 1, rp = wp ^ 1;
        const bool active = layer ? (s >= 1) : (s < TS);
        const bool window = (layer == 0) && (s + 1 < TS);
        if (active) {
            #pragma unroll
            for (int f = 0; f < 6; ++f) {
                acc_h[f] = (f32x4){0.f,0.f,0.f,0.f};
                if (layer) acc_i[f] = (f32x4){0.f,0.f,0.f,0.f};
            }

            const unsigned short* pIhi = h0hi[rp];
            const unsigned short* pIlo = h0lo[rp];
            const unsigned short* pHhi = layer ? h1hi[rp] : h0hi[rp];
            const unsigned short* pHlo = layer ? h1lo[rp] : h0lo[rp];

            // ---- batched issue: all h coherent loads (+ x stash) ----
            bf16x8 hH[4][2], hI[4][2];
            #pragma unroll
            for (int kk = 0; kk < 4; ++kk) {
                const int fo = (((mtile * 16 + (kq << 2) + kk) * 64) + lane) * 8;
                ld_coh16_issue(hH[kk][0], pHhi + fo);
                ld_coh16_issue(hH[kk][1], pHlo + fo);
                if (layer) {
                    ld_coh16_issue(hI[kk][0], pIhi + fo);
                    ld_coh16_issue(hI[kk][1], pIlo + fo);
                }
            }
            if (window) {
                #pragma unroll
                for (int kk = 0; kk < 4; ++kk) {
                    const int m = mtile * 16 + l15;
                    const int k = ((kq << 2) + kk) * 32 + (l4 << 3);
                    const float* xp = x + ((size_t)m * TS + (s + 1)) * HID + k;
                    ld16_issue(xs[kk][0], xp);
                    ld16_issue(xs[kk][1], xp + 4);
                }
            }
            wait_vm0();

            // ---- MFMAs (all operands in registers) ----
            #pragma unroll
            for (int kk = 0; kk < 4; ++kk) {
                if (layer) {
                    #pragma unroll
                    for (int f = 0; f < 6; ++f) {
                        acc_i[f] = __builtin_amdgcn_mfma_f32_16x16x32_bf16(wiR[kk][f], hI[kk][1], acc_i[f], 0, 0, 0);
                        acc_i[f] = __builtin_amdgcn_mfma_f32_16x16x32_bf16(wiR[kk][f], hI[kk][0], acc_i[f], 0, 0, 0);
                    }
                }
                #pragma unroll
                for (int f = 0; f < 6; ++f) {
                    acc_h[f] = __builtin_amdgcn_mfma_f32_16x16x32_bf16(whR[kk][f], hH[kk][1], acc_h[f], 0, 0, 0);
                    acc_h[f] = __builtin_amdgcn_mfma_f32_16x16x32_bf16(whR[kk][f], hH[kk][0], acc_h[f], 0, 0, 0);
                }
            }

            // ---- k-split reduction ----
            if (kq != 0) {
                float* p = &ldsRed[kq - 1][lane][0];
                #pragma unroll
                for (int f = 0; f < 6; ++f) {
                    *(f32x4*)(p + f * 4)      = acc_i[f];
                    *(f32x4*)(p + 24 + f * 4) = acc_h[f];
                }
            }
            __syncthreads();                   // (A)
            if (kq == 0) {
                #pragma unroll
                for (int q = 0; q < 3; ++q) {
                    const float* p = &ldsRed[q][lane][0];
                    #pragma unroll
                    for (int f = 0; f < 6; ++f) {
                        acc_i[f] += *(const f32x4*)(p + f * 4);
                        acc_h[f] += *(const f32x4*)(p + 24 + f * 4);
                    }
                }
                // ---- gates (fp32) + fragment-layout hi/lo store ----
                unsigned short* dsthi = layer ? h1hi[wp] : h0hi[wp];
                unsigned short* dstlo = layer ? h1lo[wp] : h0lo[wp];
                #pragma unroll
                for (int n2 = 0; n2 < 2; ++n2) {
                    u16x4 shi, slo; f32x4 hv;
                    #pragma unroll
                    for (int r = 0; r < 4; ++r) {
                        float vr = acc_i[n2][r]     + acc_h[n2][r]     + br[n2][r];
                        float vz = acc_i[2 + n2][r] + acc_h[2 + n2][r] + bz[n2][r];
                        float rg = sigm(vr);
                        float zg = sigm(vz);
                        float ng = tanh_(acc_i[4 + n2][r] + bni[n2][r] + rg * (acc_h[4 + n2][r] + bnh[n2][r]));
                        float h  = (1.0f - zg) * ng + zg * hold[n2][r];
                        hold[n2][r] = h;
                        hv[r] = h;
                        unsigned short hb = f2bf(h);
                        shi[r] = hb;
                        slo[r] = f2bf(h - bf2f(hb));
                    }
                    const int eo = (((mtile * 16 + ntile) * 64) + l15 + (n2 * 2 + (l4 >> 1)) * 16) * 8
                                 + (l4 & 1) * 4;
                    st_llc8(dsthi + eo, __builtin_bit_cast(unsigned long long, shi));
                    st_llc8(dstlo + eo, __builtin_bit_cast(unsigned long long, slo));
                    if (layer && s == TS) {
                        const int m = mtile * 16 + l15;
                        st_llc16(h1f + (size_t)m * HID + ntile * 32 + n2 * 16 + (l4 << 2), hv);
                    }
                }
            }
        }

        // ---- arrive: drain stores, publish seq (plain coherent store) ----
        if (tid == 0) {
            asm volatile("s_waitcnt vmcnt(0)" ::: "memory");
            __hip_atomic_store(&seqA[gidx], (unsigned)(s + 1),
                               __ATOMIC_RELAXED, __HIP_MEMORY_SCOPE_AGENT);
        }

        // ---- barrier window: L0 computes next step's x-GEMM (reg-only) ----
        if (window) do_window();

        // ---- poll: all 32 group seqs >= s+1 ----
        if (kq == 0) {
            const unsigned tgt = (unsigned)(s + 1);
            const unsigned long long* sp =
                (const unsigned long long*)(seqA + ((lane & 7) << 2));
            for (;;) {
                bool ok = true;
                if (lane < 8) {
                    unsigned long long a = __hip_atomic_load(sp,     __ATOMIC_RELAXED, __HIP_MEMORY_SCOPE_AGENT);
                    unsigned long long b = __hip_atomic_load(sp + 1, __ATOMIC_RELAXED, __HIP_MEMORY_SCOPE_AGENT);
                    ok = ((unsigned)a >= tgt) && ((unsigned)(a >> 32) >= tgt) &&
                         ((unsigned)b >= tgt) && ((unsigned)(b >> 32) >= tgt);
                }
                if (__all(ok)) break;
                __builtin_amdgcn_s_sleep(1);
            }
        }
        __syncthreads();                   // (B)
    }

    // ---- global fin barrier (one-shot), then FC epilogue ----
    if (tid == 0) {
        asm volatile("s_waitcnt vmcnt(0)" ::: "memory");
        __hip_atomic_fetch_add(fin, 1u, __ATOMIC_RELAXED, __HIP_MEMORY_SCOPE_AGENT);
    }
    if (wgid < 64) {
        float* fw = (float*)ldsRed;               // 8 rows x 516 floats
        const float* src = fcw + (size_t)wgid * 8 * HID;
        for (int i = tid; i < (8 * HID) / 4; i += WGT) {
            f32x4 v = *(const f32x4*)(src + i * 4);
            int row = (i * 4) >> 9;
            int kk  = (i * 4) & 511;
            *(f32x4*)(fw + row * 516 + kk) = v;
        }
        if (tid == 0) {
            while (__hip_atomic_load(fin, __ATOMIC_RELAXED, __HIP_MEMORY_SCOPE_AGENT) < (unsigned)NWG)
                __builtin_amdgcn_s_sleep(1);
        }
        __syncthreads();
        const int col = wgid * 8 + (tid & 7);
        const int m0  = tid >> 3;
        float a0 = fcb[col], a1 = a0, a2 = a0, a3 = a0;
        const float* fwr = fw + (tid & 7) * 516;
        for (int k = 0; k < HID; k += 4) {
            f32x4 wv  = *(const f32x4*)(fwr + k);
            f32x4 h0v = ld_coh16f(h1f + (size_t)(m0)      * HID + k);
            f32x4 h1v = ld_coh16f(h1f + (size_t)(m0 + 32) * HID + k);
            f32x4 h2v = ld_coh16f(h1f + (size_t)(m0 + 64) * HID + k);
            f32x4 h3v = ld_coh16f(h1f + (size_t)(m0 + 96) * HID + k);
            a0 += h0v[0]*wv[0] + h0v[1]*wv[1] + h0v[2]*wv[2] + h0v[3]*wv[3];
            a1 += h1v[0]*wv[0] + h1v[1]*wv[1] + h1v[2]*wv[2] + h1v[3]*wv[3];
            a2 += h2v[0]*wv[0] + h2v[1]*wv[1] + h2v[2]*wv[2] + h2v[3]*wv[3];
            a3 += h3v[0]*wv[0] + h3v[1]*wv[1] + h3v[2]*wv[2] + h3v[3]*wv[3];
        }
        out[(size_t)(m0)      * HID + col] = a0;
        out[(size_t)(m0 + 32) * HID + col] = a1;
        out[(size_t)(m0 + 64) * HID + col] = a2;
        out[(size_t)(m0 + 96) * HID + col] = a3;
    }
}

extern "C" void kernel_launch(void* const* d_in, const int* in_sizes, int n_in,
                              void* d_out, int out_size, void* d_ws, size_t ws_size,
                              hipStream_t stream) {
    (void)in_sizes; (void)n_in; (void)out_size; (void)ws_size;
    hipMemsetAsync(d_ws, 0, WS_ZERO, stream);
    gru_persistent<<<dim3(NWG), dim3(WGT), 0, stream>>>(
        (const float*)d_in[0],
        (const float*)d_in[1], (const float*)d_in[2],
        (const float*)d_in[3], (const float*)d_in[4],
        (const float*)d_in[5], (const float*)d_in[6],
        (const float*)d_in[7], (const float*)d_in[8],
        (const float*)d_in[9], (const float*)d_in[10],
        (float*)d_out, (unsigned char*)d_ws);
}